// Round 11
// baseline (180.874 us; speedup 1.0000x reference)
//
#include <hip/hip_runtime.h>
#include <hip/hip_bf16.h>
#include <math.h>

#define NH 16
#define HS 64
#define DE 1024
#define TT 1024
#define BBATCH 4
#define MTOK 4096   // B*T

typedef __bf16 v8bf __attribute__((ext_vector_type(8)));
typedef __bf16 v4bf __attribute__((ext_vector_type(4)));
typedef float  v4f  __attribute__((ext_vector_type(4)));
typedef float  v16f __attribute__((ext_vector_type(16)));

__device__ __forceinline__ void gl_lds16(const __bf16* g, __bf16* l) {
    __builtin_amdgcn_global_load_lds(
        (const __attribute__((address_space(1))) unsigned int*)g,
        (__attribute__((address_space(3))) unsigned int*)l, 16, 0, 0);
}

// ---------------- fused prep: cast x (1048576 f4), cast Wo (262144 f4), transpose Wq/Wk/Wv ----
__global__ __launch_bounds__(256) void prep_all_kernel(
    const float* __restrict__ x,  __bf16* __restrict__ xb,
    const float* __restrict__ Wo, __bf16* __restrict__ Wob,
    const float* __restrict__ Wq, const float* __restrict__ Wk,
    const float* __restrict__ Wv, __bf16* __restrict__ Wt)
{
    const int bid = blockIdx.x;
    const int t = threadIdx.x;
    if (bid < 5120) {
        int i = bid * 256 + t;
        const float* in; __bf16* out;
        if (i < 1048576) { in = x;  out = xb; }
        else             { in = Wo; out = Wob; i -= 1048576; }
        float4 v = ((const float4*)in)[i];
        v4bf o;
        o[0] = (__bf16)v.x; o[1] = (__bf16)v.y; o[2] = (__bf16)v.z; o[3] = (__bf16)v.w;
        *(v4bf*)&out[(size_t)i * 4] = o;
        return;
    }
    const int bid2 = bid - 5120;
    const int c0 = (bid2 & 15) * 64, h = (bid2 >> 4) & 15, m = bid2 >> 8;
    const float* W = (m == 0) ? Wq : (m == 1) ? Wk : Wv;
    __shared__ float tile[64][65];
    #pragma unroll
    for (int pp = 0; pp < 16; ++pp) {
        int cl = pp * 4 + (t >> 6);
        int s  = t & 63;
        tile[cl][s] = W[((size_t)h * DE + c0 + cl) * HS + s];
    }
    __syncthreads();
    #pragma unroll
    for (int pp = 0; pp < 16; ++pp) {
        int s  = pp * 4 + (t >> 6);
        int cl = t & 63;
        Wt[((size_t)(m * DE + h * HS + s)) * DE + c0 + cl] = (__bf16)tile[cl][s];
    }
}

// -------- 128x128 MFMA GEMM: BK=64 dbuf + XCD swizzle + XOR bank swizzle (r6, validated) --------
__device__ __forceinline__ void gemm_stage(
    const __bf16* __restrict__ Ab, const __bf16* __restrict__ Bb,
    __bf16* As, __bf16* Bs, int K, int k0, int w, int l)
{
    #pragma unroll
    for (int i = 0; i < 4; ++i) {
        int p   = i * 256 + w * 64 + l;
        int row = p >> 3;
        int lc  = (p & 7) ^ (row & 7);
        gl_lds16(Ab + (size_t)row * K + k0 + lc * 8, As + p * 8);
        gl_lds16(Bb + (size_t)row * K + k0 + lc * 8, Bs + p * 8);
    }
}

__global__ __launch_bounds__(256) void gemm_bt_kernel(
    const __bf16* __restrict__ A, const __bf16* __restrict__ Bt,
    int K, int mode,
    __bf16* __restrict__ qk_out, __bf16* __restrict__ vt_out,
    float* __restrict__ f_out, const float* __restrict__ bias)
{
    __shared__ __align__(16) __bf16 As[2][128 * 64];
    __shared__ __align__(16) __bf16 Bs[2][128 * 64];
    const int tid = threadIdx.x;
    const int w = tid >> 6, l = tid & 63;
    const int wm = w >> 1, wn = w & 1;
    const int lhi = l >> 4, llo = l & 15;
    const int sw0 = ((lhi ^ (llo & 7)) << 3);
    const int sw1 = sw0 ^ 32;

    const int lin = blockIdx.x;
    const int xcd = lin & 7, j = lin >> 3;
    const int bm = xcd * 4 + (j & 3);
    const int bn = j >> 2;

    v4f acc[4][4];
    #pragma unroll
    for (int i = 0; i < 4; ++i)
        #pragma unroll
        for (int jj = 0; jj < 4; ++jj)
            #pragma unroll
            for (int r = 0; r < 4; ++r) acc[i][jj][r] = 0.f;

    const __bf16* Ab = A  + (size_t)bm * 128 * K;
    const __bf16* Bb = Bt + (size_t)bn * 128 * K;

    const int niter = K >> 6;
    gemm_stage(Ab, Bb, As[0], Bs[0], K, 0, w, l);

    for (int it = 0; it < niter; ++it) {
        const int buf = it & 1;
        __syncthreads();
        if (it + 1 < niter)
            gemm_stage(Ab, Bb, As[buf ^ 1], Bs[buf ^ 1], K, (it + 1) * 64, w, l);
        #pragma unroll
        for (int kk = 0; kk < 64; kk += 32) {
            const int sw = kk ? sw1 : sw0;
            v8bf a[4], b[4];
            #pragma unroll
            for (int i = 0; i < 4; ++i)
                a[i] = *(const v8bf*)&As[buf][(wm * 64 + i * 16 + llo) * 64 + sw];
            #pragma unroll
            for (int jj = 0; jj < 4; ++jj)
                b[jj] = *(const v8bf*)&Bs[buf][(wn * 64 + jj * 16 + llo) * 64 + sw];
            #pragma unroll
            for (int i = 0; i < 4; ++i)
                #pragma unroll
                for (int jj = 0; jj < 4; ++jj)
                    acc[i][jj] = __builtin_amdgcn_mfma_f32_16x16x32_bf16(a[i], b[jj], acc[i][jj], 0, 0, 0);
        }
    }

    const int row0 = bm * 128 + wm * 64;
    const int col0 = bn * 128 + wn * 64;

    if (mode == 0) {
        if (col0 < 2048) {   // Q / K region
            #pragma unroll
            for (int i = 0; i < 4; ++i) {
                int rbase = row0 + i * 16 + lhi * 4;
                #pragma unroll
                for (int jj = 0; jj < 4; ++jj) {
                    int c = col0 + jj * 16 + llo;
                    #pragma unroll
                    for (int r = 0; r < 4; ++r)
                        qk_out[(size_t)(rbase + r) * 2048 + c] = (__bf16)acc[i][jj][r];
                }
            }
        } else {             // V region -> vt[(b*16+h)*64+s][t]
            #pragma unroll
            for (int i = 0; i < 4; ++i) {
                int rbase = row0 + i * 16 + lhi * 4;
                int bidx = rbase >> 10, t0 = rbase & 1023;
                #pragma unroll
                for (int jj = 0; jj < 4; ++jj) {
                    int c = col0 + jj * 16 + llo - 2048;
                    v4bf pk;
                    #pragma unroll
                    for (int r = 0; r < 4; ++r) pk[r] = (__bf16)acc[i][jj][r];
                    *(v4bf*)&vt_out[((size_t)(bidx * NH + (c >> 6)) * HS + (c & 63)) * TT + t0] = pk;
                }
            }
        }
    } else {
        #pragma unroll
        for (int jj = 0; jj < 4; ++jj) {
            int c = col0 + jj * 16 + llo;
            float bv = bias[c];
            #pragma unroll
            for (int i = 0; i < 4; ++i) {
                int rbase = row0 + i * 16 + lhi * 4;
                #pragma unroll
                for (int r = 0; r < 4; ++r)
                    f_out[(size_t)(rbase + r) * DE + c] = acc[i][jj][r] + bv;
            }
        }
    }
}

// -------- flash attention v7: 32x32x16 MFMA, wave = 32 q-rows, block = 128 q-rows --------
// DS traffic per row ~0.56x of the 16x16 version (20 b128 per 32 rows vs 36), MFMA issues
// per row halved. C/D layout: col=lane&31, row=(reg&3)+8*(reg>>2)+4*(lane>>5) [HW-verified].
// A/B layout: X[idx=lane&31][k=(lane>>5)*8+j] (generalization of verified 16x16x32 pattern).
__device__ __forceinline__ v16f bf_mfma32(v8bf a, v8bf b, v16f c) {
    return __builtin_amdgcn_mfma_f32_32x32x16_bf16(a, b, c, 0, 0, 0);
}

__device__ __forceinline__ void stage_kv(
    const __bf16* __restrict__ kb, const __bf16* __restrict__ vb,
    __bf16* Ksb, __bf16* Vsb, int k0, int tid)
{
    #pragma unroll
    for (int i = 0; i < 2; ++i) {
        int p   = i * 256 + tid;
        int row = p >> 3;
        int lc  = (p & 7) ^ (row & 7);
        gl_lds16(kb + (size_t)(k0 + row) * 2048 + lc * 8, Ksb + p * 8);
        gl_lds16(vb + (size_t)row * TT + k0 + lc * 8,     Vsb + p * 8);
    }
}

__global__ __launch_bounds__(256) void attn_kernel(
    const __bf16* __restrict__ qk, const __bf16* __restrict__ vt,
    __bf16* __restrict__ att)
{
    __shared__ __align__(16) __bf16 Ks[2][64 * 64];
    __shared__ __align__(16) __bf16 Vs[2][64 * 64];
    __shared__ __align__(16) __bf16 Ps[4][32 * 72];   // stride 72: rows rotate 4 banks

    const int tid = threadIdx.x;
    const int w = tid >> 6, l = tid & 63;
    const int m = l & 31, hh = l >> 5;
    const int bh = blockIdx.x & 63;          // same-bh blocks 64 apart -> same XCD
    const int st = 7 - (blockIdx.x >> 6);    // longest blocks launch first
    const int b = bh >> 4, hd = bh & 15;

    const __bf16* qbase = qk + (size_t)b * TT * 2048 + hd * HS;
    const __bf16* kbase = qk + (size_t)b * TT * 2048 + 1024 + hd * HS;
    const __bf16* vbase = vt + (size_t)bh * HS * TT;
    __bf16* PsW = &Ps[w][0];

    const int r0 = st * 128 + w * 32;

    // per-k-step swizzled chunk offsets for K/V fragment reads (XOR layout from stage_kv)
    int offs[4];
    #pragma unroll
    for (int s = 0; s < 4; ++s) offs[s] = (((2 * s + hh) ^ (m & 7)) << 3);

    stage_kv(kbase, vbase, Ks[0], Vs[0], 0, tid);

    // Q fragments (loop-invariant): A[m][k=s*16+hh*8+j]
    v8bf aq[4];
    #pragma unroll
    for (int s = 0; s < 4; ++s)
        aq[s] = *(const v8bf*)&qbase[(size_t)(r0 + m) * 2048 + s * 16 + hh * 8];

    float l_part[16];
    #pragma unroll
    for (int r = 0; r < 16; ++r) l_part[r] = 0.f;
    v16f o0, o1;
    #pragma unroll
    for (int r = 0; r < 16; ++r) { o0[r] = 0.f; o1[r] = 0.f; }

    const int ntiles = 2 * st + 2;
    for (int kt = 0; kt < ntiles; ++kt) {
        const int buf = kt & 1;
        const int k0 = kt * 64;
        __syncthreads();                     // drains own gl_lds for tile kt
        if (kt + 1 < ntiles)
            stage_kv(kbase, vbase, Ks[buf ^ 1], Vs[buf ^ 1], (kt + 1) * 64, tid);

        const __bf16* Ksb = Ks[buf];
        const __bf16* Vsb = Vs[buf];

        // S = Q K^T (2 n-tiles x 4 k-steps)
        v16f s0, s1;
        #pragma unroll
        for (int r = 0; r < 16; ++r) { s0[r] = 0.f; s1[r] = 0.f; }
        #pragma unroll
        for (int s = 0; s < 4; ++s) {
            v8bf bk0 = *(const v8bf*)&Ksb[m * 64 + offs[s]];
            v8bf bk1 = *(const v8bf*)&Ksb[(32 + m) * 64 + offs[s]];
            s0 = bf_mfma32(aq[s], bk0, s0);
            s1 = bf_mfma32(aq[s], bk1, s1);
        }

        // P = exp2(S * 0.125*log2 e), mask on diagonal tiles, write to per-wave LDS
        const bool diag = (kt >= 2 * st);
        #pragma unroll
        for (int r = 0; r < 16; ++r) {
            int row  = (r & 3) + 8 * (r >> 2) + 4 * hh;
            int rowg = r0 + row;
            float a0 = s0[r] * 0.18033688f;
            float a1 = s1[r] * 0.18033688f;
            if (diag) {
                if (k0 + m > rowg)      a0 = -1e30f;
                if (k0 + 32 + m > rowg) a1 = -1e30f;
            }
            float p0 = exp2f(a0), p1 = exp2f(a1);
            l_part[r] += p0 + p1;
            PsW[row * 72 + m]      = (__bf16)p0;
            PsW[row * 72 + 32 + m] = (__bf16)p1;
        }

        // O += P V
        #pragma unroll
        for (int s = 0; s < 4; ++s) {
            v8bf ap  = *(const v8bf*)&PsW[m * 72 + s * 16 + hh * 8];
            v8bf bv0 = *(const v8bf*)&Vsb[m * 64 + offs[s]];
            v8bf bv1 = *(const v8bf*)&Vsb[(32 + m) * 64 + offs[s]];
            o0 = bf_mfma32(ap, bv0, o0);
            o1 = bf_mfma32(ap, bv1, o1);
        }
    }

    // reduce l over the 32-lane half (rows are half-local), normalize, store
    #pragma unroll
    for (int r = 0; r < 16; ++r) {
        float s = l_part[r];
        #pragma unroll
        for (int msk = 1; msk < 32; msk <<= 1) s += __shfl_xor(s, msk, 64);
        float inv = 1.f / s;
        int row = (r & 3) + 8 * (r >> 2) + 4 * hh;
        size_t rowg = (size_t)(b * TT + r0 + row);
        att[rowg * DE + hd * HS + m]      = (__bf16)(o0[r] * inv);
        att[rowg * DE + hd * HS + 32 + m] = (__bf16)(o1[r] * inv);
    }
}

extern "C" void kernel_launch(void* const* d_in, const int* in_sizes, int n_in,
                              void* d_out, int out_size, void* d_ws, size_t ws_size,
                              hipStream_t stream)
{
    const float* x  = (const float*)d_in[0];
    const float* Wq = (const float*)d_in[1];
    const float* Wk = (const float*)d_in[2];
    const float* Wv = (const float*)d_in[3];
    const float* Wo = (const float*)d_in[4];
    const float* bo = (const float*)d_in[5];
    float* out = (float*)d_out;

    char* ws = (char*)d_ws;
    __bf16* xb  = (__bf16*)(ws);                 // 8 MB   [4096][1024]
    __bf16* Wt  = (__bf16*)(ws + 8388608);       // 6 MB   [3072][1024]
    __bf16* Wob = (__bf16*)(ws + 14680064);      // 2 MB   [1024][1024]
    __bf16* qk  = (__bf16*)(ws + 16777216);      // 16 MB  [4096][2048]
    __bf16* vt  = (__bf16*)(ws + 33554432);      // 8 MB   [64][64][1024]
    __bf16* att = (__bf16*)(ws + 41943040);      // 8 MB   [4096][1024]

    // fused prep: casts (5120 blocks) + weight transpose (768 blocks)
    prep_all_kernel<<<5888, 256, 0, stream>>>(x, xb, Wo, Wob, Wq, Wk, Wv, Wt);
    // QKV: M=4096, N=3072, K=1024 -> 768 blocks (8 xcd x 4 bm x 24 bn)
    gemm_bt_kernel<<<768, 256, 0, stream>>>(xb, Wt, 1024, 0, qk, vt, nullptr, nullptr);
    // attention: 512 blocks = 64 bh x 8 128-row q-supertiles, longest first
    attn_kernel<<<512, 256, 0, stream>>>(qk, vt, att);
    // out proj: M=4096, N=1024, K=1024 -> 256 blocks (8 xcd x 4 bm x 8 bn)
    gemm_bt_kernel<<<256, 256, 0, stream>>>(att, Wob, 1024, 1, nullptr, nullptr, out, bo);
}

// Round 12
// 163.644 us; speedup vs baseline: 1.1053x; 1.1053x over previous
//
#include <hip/hip_runtime.h>
#include <hip/hip_bf16.h>
#include <math.h>

#define NH 16
#define HS 64
#define DE 1024
#define TT 1024
#define BBATCH 4
#define MTOK 4096   // B*T

typedef __bf16 v8bf __attribute__((ext_vector_type(8)));
typedef __bf16 v4bf __attribute__((ext_vector_type(4)));
typedef float  v4f  __attribute__((ext_vector_type(4)));

__device__ __forceinline__ void gl_lds16(const __bf16* g, __bf16* l) {
    __builtin_amdgcn_global_load_lds(
        (const __attribute__((address_space(1))) unsigned int*)g,
        (__attribute__((address_space(3))) unsigned int*)l, 16, 0, 0);
}

// ---------------- fused prep: cast x (1048576 f4), cast Wo (262144 f4), transpose Wq/Wk/Wv ----
__global__ __launch_bounds__(256) void prep_all_kernel(
    const float* __restrict__ x,  __bf16* __restrict__ xb,
    const float* __restrict__ Wo, __bf16* __restrict__ Wob,
    const float* __restrict__ Wq, const float* __restrict__ Wk,
    const float* __restrict__ Wv, __bf16* __restrict__ Wt)
{
    const int bid = blockIdx.x;
    const int t = threadIdx.x;
    if (bid < 5120) {
        int i = bid * 256 + t;
        const float* in; __bf16* out;
        if (i < 1048576) { in = x;  out = xb; }
        else             { in = Wo; out = Wob; i -= 1048576; }
        float4 v = ((const float4*)in)[i];
        v4bf o;
        o[0] = (__bf16)v.x; o[1] = (__bf16)v.y; o[2] = (__bf16)v.z; o[3] = (__bf16)v.w;
        *(v4bf*)&out[(size_t)i * 4] = o;
        return;
    }
    const int bid2 = bid - 5120;
    const int c0 = (bid2 & 15) * 64, h = (bid2 >> 4) & 15, m = bid2 >> 8;
    const float* W = (m == 0) ? Wq : (m == 1) ? Wk : Wv;
    __shared__ float tile[64][65];
    #pragma unroll
    for (int pp = 0; pp < 16; ++pp) {
        int cl = pp * 4 + (t >> 6);
        int s  = t & 63;
        tile[cl][s] = W[((size_t)h * DE + c0 + cl) * HS + s];
    }
    __syncthreads();
    #pragma unroll
    for (int pp = 0; pp < 16; ++pp) {
        int s  = pp * 4 + (t >> 6);
        int cl = t & 63;
        Wt[((size_t)(m * DE + h * HS + s)) * DE + c0 + cl] = (__bf16)tile[cl][s];
    }
}

// -------- 128x128 MFMA GEMM: BK=64 dbuf + XCD swizzle + XOR bank swizzle (r6, validated) --------
__device__ __forceinline__ void gemm_stage(
    const __bf16* __restrict__ Ab, const __bf16* __restrict__ Bb,
    __bf16* As, __bf16* Bs, int K, int k0, int w, int l)
{
    #pragma unroll
    for (int i = 0; i < 4; ++i) {
        int p   = i * 256 + w * 64 + l;
        int row = p >> 3;
        int lc  = (p & 7) ^ (row & 7);
        gl_lds16(Ab + (size_t)row * K + k0 + lc * 8, As + p * 8);
        gl_lds16(Bb + (size_t)row * K + k0 + lc * 8, Bs + p * 8);
    }
}

__global__ __launch_bounds__(256) void gemm_bt_kernel(
    const __bf16* __restrict__ A, const __bf16* __restrict__ Bt,
    int K,
    __bf16* __restrict__ qk_out, __bf16* __restrict__ vt_out)
{
    __shared__ __align__(16) __bf16 As[2][128 * 64];
    __shared__ __align__(16) __bf16 Bs[2][128 * 64];
    const int tid = threadIdx.x;
    const int w = tid >> 6, l = tid & 63;
    const int wm = w >> 1, wn = w & 1;
    const int lhi = l >> 4, llo = l & 15;
    const int sw0 = ((lhi ^ (llo & 7)) << 3);
    const int sw1 = sw0 ^ 32;

    const int lin = blockIdx.x;
    const int xcd = lin & 7, j = lin >> 3;
    const int bm = xcd * 4 + (j & 3);
    const int bn = j >> 2;

    v4f acc[4][4];
    #pragma unroll
    for (int i = 0; i < 4; ++i)
        #pragma unroll
        for (int jj = 0; jj < 4; ++jj)
            #pragma unroll
            for (int r = 0; r < 4; ++r) acc[i][jj][r] = 0.f;

    const __bf16* Ab = A  + (size_t)bm * 128 * K;
    const __bf16* Bb = Bt + (size_t)bn * 128 * K;

    const int niter = K >> 6;
    gemm_stage(Ab, Bb, As[0], Bs[0], K, 0, w, l);

    for (int it = 0; it < niter; ++it) {
        const int buf = it & 1;
        __syncthreads();
        if (it + 1 < niter)
            gemm_stage(Ab, Bb, As[buf ^ 1], Bs[buf ^ 1], K, (it + 1) * 64, w, l);
        #pragma unroll
        for (int kk = 0; kk < 64; kk += 32) {
            const int sw = kk ? sw1 : sw0;
            v8bf a[4], b[4];
            #pragma unroll
            for (int i = 0; i < 4; ++i)
                a[i] = *(const v8bf*)&As[buf][(wm * 64 + i * 16 + llo) * 64 + sw];
            #pragma unroll
            for (int jj = 0; jj < 4; ++jj)
                b[jj] = *(const v8bf*)&Bs[buf][(wn * 64 + jj * 16 + llo) * 64 + sw];
            #pragma unroll
            for (int i = 0; i < 4; ++i)
                #pragma unroll
                for (int jj = 0; jj < 4; ++jj)
                    acc[i][jj] = __builtin_amdgcn_mfma_f32_16x16x32_bf16(a[i], b[jj], acc[i][jj], 0, 0, 0);
        }
    }

    const int row0 = bm * 128 + wm * 64;
    const int col0 = bn * 128 + wn * 64;

    if (col0 < 2048) {   // Q / K region
        #pragma unroll
        for (int i = 0; i < 4; ++i) {
            int rbase = row0 + i * 16 + lhi * 4;
            #pragma unroll
            for (int jj = 0; jj < 4; ++jj) {
                int c = col0 + jj * 16 + llo;
                #pragma unroll
                for (int r = 0; r < 4; ++r)
                    qk_out[(size_t)(rbase + r) * 2048 + c] = (__bf16)acc[i][jj][r];
            }
        }
    } else {             // V region -> vt[(b*16+h)*64+s][t]
        #pragma unroll
        for (int i = 0; i < 4; ++i) {
            int rbase = row0 + i * 16 + lhi * 4;
            int bidx = rbase >> 10, t0 = rbase & 1023;
            #pragma unroll
            for (int jj = 0; jj < 4; ++jj) {
                int c = col0 + jj * 16 + llo - 2048;
                v4bf pk;
                #pragma unroll
                for (int r = 0; r < 4; ++r) pk[r] = (__bf16)acc[i][jj][r];
                *(v4bf*)&vt_out[((size_t)(bidx * NH + (c >> 6)) * HS + (c & 63)) * TT + t0] = pk;
            }
        }
    }
}

// -------- out-proj GEMM: 64x128 tiles -> 512 blocks (2 waves/SIMD vs 1 at 128x128) --------
// The 256-block version ran 1 block/CU = 1 wave/SIMD: zero TLP, every drain exposed.
__global__ __launch_bounds__(256) void gemm_bt64_kernel(
    const __bf16* __restrict__ A, const __bf16* __restrict__ Bt, int K,
    float* __restrict__ f_out, const float* __restrict__ bias)
{
    __shared__ __align__(16) __bf16 As[2][64 * 64];
    __shared__ __align__(16) __bf16 Bs[2][128 * 64];
    const int tid = threadIdx.x;
    const int w = tid >> 6, l = tid & 63;
    const int wm = w & 1, wn = w >> 1;
    const int lhi = l >> 4, llo = l & 15;
    const int sw0 = ((lhi ^ (llo & 7)) << 3);
    const int sw1 = sw0 ^ 32;

    // lin = xcd + 8*(bmi + 8*bn); xcd owns 8 bm-tiles (512 rows, 1MB A slab)
    const int lin = blockIdx.x;
    const int xcd = lin & 7, j = lin >> 3;
    const int bm = xcd * 8 + (j & 7);
    const int bn = j >> 3;

    v4f acc[2][4];
    #pragma unroll
    for (int i = 0; i < 2; ++i)
        #pragma unroll
        for (int jj = 0; jj < 4; ++jj)
            #pragma unroll
            for (int r = 0; r < 4; ++r) acc[i][jj][r] = 0.f;

    const __bf16* Ab = A  + (size_t)bm * 64 * K;
    const __bf16* Bb = Bt + (size_t)bn * 128 * K;

    const int niter = K >> 6;
    // stage tile 0
    {
        #pragma unroll
        for (int i = 0; i < 2; ++i) {
            int p = i * 256 + tid, row = p >> 3, lc = (p & 7) ^ (row & 7);
            gl_lds16(Ab + (size_t)row * K + lc * 8, As[0] + p * 8);
        }
        #pragma unroll
        for (int i = 0; i < 4; ++i) {
            int p = i * 256 + tid, row = p >> 3, lc = (p & 7) ^ (row & 7);
            gl_lds16(Bb + (size_t)row * K + lc * 8, Bs[0] + p * 8);
        }
    }

    for (int it = 0; it < niter; ++it) {
        const int buf = it & 1;
        __syncthreads();
        if (it + 1 < niter) {
            const int k0 = (it + 1) * 64;
            #pragma unroll
            for (int i = 0; i < 2; ++i) {
                int p = i * 256 + tid, row = p >> 3, lc = (p & 7) ^ (row & 7);
                gl_lds16(Ab + (size_t)row * K + k0 + lc * 8, As[buf ^ 1] + p * 8);
            }
            #pragma unroll
            for (int i = 0; i < 4; ++i) {
                int p = i * 256 + tid, row = p >> 3, lc = (p & 7) ^ (row & 7);
                gl_lds16(Bb + (size_t)row * K + k0 + lc * 8, Bs[buf ^ 1] + p * 8);
            }
        }
        #pragma unroll
        for (int kk = 0; kk < 64; kk += 32) {
            const int sw = kk ? sw1 : sw0;
            v8bf a[2], b[4];
            #pragma unroll
            for (int i = 0; i < 2; ++i)
                a[i] = *(const v8bf*)&As[buf][(wm * 32 + i * 16 + llo) * 64 + sw];
            #pragma unroll
            for (int jj = 0; jj < 4; ++jj)
                b[jj] = *(const v8bf*)&Bs[buf][(wn * 64 + jj * 16 + llo) * 64 + sw];
            #pragma unroll
            for (int i = 0; i < 2; ++i)
                #pragma unroll
                for (int jj = 0; jj < 4; ++jj)
                    acc[i][jj] = __builtin_amdgcn_mfma_f32_16x16x32_bf16(a[i], b[jj], acc[i][jj], 0, 0, 0);
        }
    }

    const int row0 = bm * 64 + wm * 32;
    const int col0 = bn * 128 + wn * 64;
    #pragma unroll
    for (int jj = 0; jj < 4; ++jj) {
        int c = col0 + jj * 16 + llo;
        float bv = bias[c];
        #pragma unroll
        for (int i = 0; i < 2; ++i) {
            int rbase = row0 + i * 16 + lhi * 4;
            #pragma unroll
            for (int r = 0; r < 4; ++r)
                f_out[(size_t)(rbase + r) * DE + c] = acc[i][jj][r] + bv;
        }
    }
}

// ---------------- flash attention v4 (r6/r10-validated best): dbuf staging + XOR swizzle ----------------
__device__ __forceinline__ v4f bf_mfma(v8bf a, v8bf b, v4f c) {
    return __builtin_amdgcn_mfma_f32_16x16x32_bf16(a, b, c, 0, 0, 0);
}

__device__ __forceinline__ void stage_kv(
    const __bf16* __restrict__ kb, const __bf16* __restrict__ vb,
    __bf16* Ksb, __bf16* Vsb, int k0, int tid)
{
    #pragma unroll
    for (int i = 0; i < 2; ++i) {
        int p   = i * 256 + tid;
        int row = p >> 3;
        int lc  = (p & 7) ^ (row & 7);
        gl_lds16(kb + (size_t)(k0 + row) * 2048 + lc * 8, Ksb + p * 8);
        gl_lds16(vb + (size_t)row * TT + k0 + lc * 8,     Vsb + p * 8);
    }
}

template<bool DIAG>
__device__ __forceinline__ void attn_compute(
    const __bf16* __restrict__ Ksb, const __bf16* __restrict__ Vsb,
    __bf16* __restrict__ PsW, int k0, int r0, int lhi, int llo, int sw0, int sw1,
    v8bf aq0, v8bf aq1, v4f (&o)[4], float (&l_part)[4])
{
    v4f sacc[4];
    #pragma unroll
    for (int n = 0; n < 4; ++n)
        #pragma unroll
        for (int r = 0; r < 4; ++r) sacc[n][r] = 0.f;
    #pragma unroll
    for (int n = 0; n < 4; ++n) {
        v8bf bk0 = *(const v8bf*)&Ksb[(n * 16 + llo) * 64 + sw0];
        v8bf bk1 = *(const v8bf*)&Ksb[(n * 16 + llo) * 64 + sw1];
        sacc[n] = bf_mfma(aq0, bk0, sacc[n]);
        sacc[n] = bf_mfma(aq1, bk1, sacc[n]);
    }

    float prob[4][4];
    #pragma unroll
    for (int n = 0; n < 4; ++n) {
        int colg = k0 + n * 16 + llo;
        #pragma unroll
        for (int r = 0; r < 4; ++r) {
            float s2 = sacc[n][r] * 0.18033688f;   // 0.125 * log2(e)
            if (DIAG) { int rowg = r0 + lhi * 4 + r; if (colg > rowg) s2 = -1e30f; }
            float p = exp2f(s2);
            prob[n][r] = p;
            l_part[r] += p;
        }
    }

    #pragma unroll
    for (int r = 0; r < 4; ++r)
        #pragma unroll
        for (int n = 0; n < 4; ++n)
            PsW[(lhi * 4 + r) * 72 + n * 16 + llo] = (__bf16)prob[n][r];

    #pragma unroll
    for (int kk = 0; kk < 64; kk += 32) {
        v8bf ap = *(const v8bf*)&PsW[llo * 72 + kk + lhi * 8];
        const int sw = kk ? sw1 : sw0;
        #pragma unroll
        for (int n = 0; n < 4; ++n) {
            v8bf bv = *(const v8bf*)&Vsb[(n * 16 + llo) * 64 + sw];
            o[n] = bf_mfma(ap, bv, o[n]);
        }
    }
}

__global__ __launch_bounds__(256) void attn_kernel(
    const __bf16* __restrict__ qk, const __bf16* __restrict__ vt,
    __bf16* __restrict__ att)
{
    __shared__ __align__(16) __bf16 Ks[2][64 * 64];
    __shared__ __align__(16) __bf16 Vs[2][64 * 64];
    __shared__ __align__(16) __bf16 Ps[4][16 * 72];

    const int tid = threadIdx.x;
    const int w = tid >> 6, l = tid & 63;
    const int lhi = l >> 4, llo = l & 15;
    const int sw0 = ((lhi ^ (llo & 7)) << 3);
    const int sw1 = sw0 ^ 32;
    const int bh = blockIdx.x & 63;          // same-bh blocks 64 apart -> same XCD
    const int qt = 15 - (blockIdx.x >> 6);   // longest blocks launch first
    const int b = bh >> 4, h = bh & 15;

    const __bf16* qbase = qk + (size_t)b * TT * 2048 + h * HS;
    const __bf16* kbase = qk + (size_t)b * TT * 2048 + 1024 + h * HS;
    const __bf16* vbase = vt + (size_t)bh * HS * TT;
    __bf16* PsW = &Ps[w][0];

    const int r0 = qt * 64 + w * 16;

    stage_kv(kbase, vbase, Ks[0], Vs[0], 0, tid);

    v8bf aq0 = *(const v8bf*)&qbase[(size_t)(r0 + llo) * 2048 + lhi * 8];
    v8bf aq1 = *(const v8bf*)&qbase[(size_t)(r0 + llo) * 2048 + 32 + lhi * 8];

    float l_part[4] = {0.f, 0.f, 0.f, 0.f};
    v4f o[4];
    #pragma unroll
    for (int n = 0; n < 4; ++n)
        #pragma unroll
        for (int r = 0; r < 4; ++r) o[n][r] = 0.f;

    for (int kt = 0; kt < qt; ++kt) {
        const int buf = kt & 1;
        __syncthreads();
        stage_kv(kbase, vbase, Ks[buf ^ 1], Vs[buf ^ 1], (kt + 1) * 64, tid);
        attn_compute<false>(Ks[buf], Vs[buf], PsW, kt * 64, r0, lhi, llo, sw0, sw1, aq0, aq1, o, l_part);
    }
    __syncthreads();
    attn_compute<true>(Ks[qt & 1], Vs[qt & 1], PsW, qt * 64, r0, lhi, llo, sw0, sw1, aq0, aq1, o, l_part);

    #pragma unroll
    for (int r = 0; r < 4; ++r) {
        float s = l_part[r];
        #pragma unroll
        for (int msk = 1; msk < 16; msk <<= 1) s += __shfl_xor(s, msk, 64);
        float inv = 1.f / s;
        int rowg = b * TT + r0 + lhi * 4 + r;
        #pragma unroll
        for (int n = 0; n < 4; ++n)
            att[(size_t)rowg * DE + h * HS + n * 16 + llo] = (__bf16)(o[n][r] * inv);
    }
}

extern "C" void kernel_launch(void* const* d_in, const int* in_sizes, int n_in,
                              void* d_out, int out_size, void* d_ws, size_t ws_size,
                              hipStream_t stream)
{
    const float* x  = (const float*)d_in[0];
    const float* Wq = (const float*)d_in[1];
    const float* Wk = (const float*)d_in[2];
    const float* Wv = (const float*)d_in[3];
    const float* Wo = (const float*)d_in[4];
    const float* bo = (const float*)d_in[5];
    float* out = (float*)d_out;

    char* ws = (char*)d_ws;
    __bf16* xb  = (__bf16*)(ws);                 // 8 MB   [4096][1024]
    __bf16* Wt  = (__bf16*)(ws + 8388608);       // 6 MB   [3072][1024]
    __bf16* Wob = (__bf16*)(ws + 14680064);      // 2 MB   [1024][1024]
    __bf16* qk  = (__bf16*)(ws + 16777216);      // 16 MB  [4096][2048]
    __bf16* vt  = (__bf16*)(ws + 33554432);      // 8 MB   [64][64][1024]
    __bf16* att = (__bf16*)(ws + 41943040);      // 8 MB   [4096][1024]

    // fused prep: casts (5120 blocks) + weight transpose (768 blocks)
    prep_all_kernel<<<5888, 256, 0, stream>>>(x, xb, Wo, Wob, Wq, Wk, Wv, Wt);
    // QKV: M=4096, N=3072, K=1024 -> 768 blocks (8 xcd x 4 bm x 24 bn)
    gemm_bt_kernel<<<768, 256, 0, stream>>>(xb, Wt, 1024, qk, vt);
    // attention: 1024 blocks = 64 bh x 16 q-supertiles, longest first
    attn_kernel<<<1024, 256, 0, stream>>>(qk, vt, att);
    // out proj: M=4096, N=1024, K=1024 -> 512 blocks (8 xcd x 8 bm x 8 bn), 64x128 tiles
    gemm_bt64_kernel<<<512, 256, 0, stream>>>(att, Wob, 1024, out, bo);
}

// Round 13
// 157.101 us; speedup vs baseline: 1.1513x; 1.0416x over previous
//
#include <hip/hip_runtime.h>
#include <hip/hip_bf16.h>
#include <math.h>

#define NH 16
#define HS 64
#define DE 1024
#define TT 1024
#define BBATCH 4
#define MTOK 4096   // B*T

typedef __bf16 v8bf __attribute__((ext_vector_type(8)));
typedef __bf16 v4bf __attribute__((ext_vector_type(4)));
typedef float  v4f  __attribute__((ext_vector_type(4)));

__device__ __forceinline__ void gl_lds16(const __bf16* g, __bf16* l) {
    __builtin_amdgcn_global_load_lds(
        (const __attribute__((address_space(1))) unsigned int*)g,
        (__attribute__((address_space(3))) unsigned int*)l, 16, 0, 0);
}

// ---------------- fused prep: cast x (1048576 f4), cast Wo (262144 f4), transpose Wq/Wk/Wv ----
__global__ __launch_bounds__(256) void prep_all_kernel(
    const float* __restrict__ x,  __bf16* __restrict__ xb,
    const float* __restrict__ Wo, __bf16* __restrict__ Wob,
    const float* __restrict__ Wq, const float* __restrict__ Wk,
    const float* __restrict__ Wv, __bf16* __restrict__ Wt)
{
    const int bid = blockIdx.x;
    const int t = threadIdx.x;
    if (bid < 5120) {
        int i = bid * 256 + t;
        const float* in; __bf16* out;
        if (i < 1048576) { in = x;  out = xb; }
        else             { in = Wo; out = Wob; i -= 1048576; }
        float4 v = ((const float4*)in)[i];
        v4bf o;
        o[0] = (__bf16)v.x; o[1] = (__bf16)v.y; o[2] = (__bf16)v.z; o[3] = (__bf16)v.w;
        *(v4bf*)&out[(size_t)i * 4] = o;
        return;
    }
    const int bid2 = bid - 5120;
    const int c0 = (bid2 & 15) * 64, h = (bid2 >> 4) & 15, m = bid2 >> 8;
    const float* W = (m == 0) ? Wq : (m == 1) ? Wk : Wv;
    __shared__ float tile[64][65];
    #pragma unroll
    for (int pp = 0; pp < 16; ++pp) {
        int cl = pp * 4 + (t >> 6);
        int s  = t & 63;
        tile[cl][s] = W[((size_t)h * DE + c0 + cl) * HS + s];
    }
    __syncthreads();
    #pragma unroll
    for (int pp = 0; pp < 16; ++pp) {
        int s  = pp * 4 + (t >> 6);
        int cl = t & 63;
        Wt[((size_t)(m * DE + h * HS + s)) * DE + c0 + cl] = (__bf16)tile[cl][s];
    }
}

// -------- QKV GEMM: 128x128, SINGLE-buffer m97 2-barrier K-loop (32KB LDS -> 3 blocks/CU,
// whole 768-block grid co-resident, no tail) + XCD swizzle + XOR bank swizzle --------
__device__ __forceinline__ void gemm_stage(
    const __bf16* __restrict__ Ab, const __bf16* __restrict__ Bb,
    __bf16* As, __bf16* Bs, int K, int k0, int w, int l)
{
    #pragma unroll
    for (int i = 0; i < 4; ++i) {
        int p   = i * 256 + w * 64 + l;
        int row = p >> 3;
        int lc  = (p & 7) ^ (row & 7);
        gl_lds16(Ab + (size_t)row * K + k0 + lc * 8, As + p * 8);
        gl_lds16(Bb + (size_t)row * K + k0 + lc * 8, Bs + p * 8);
    }
}

__global__ __launch_bounds__(256) void gemm_bt_kernel(
    const __bf16* __restrict__ A, const __bf16* __restrict__ Bt,
    int K,
    __bf16* __restrict__ qk_out, __bf16* __restrict__ vt_out)
{
    __shared__ __align__(16) __bf16 As[128 * 64];
    __shared__ __align__(16) __bf16 Bs[128 * 64];
    const int tid = threadIdx.x;
    const int w = tid >> 6, l = tid & 63;
    const int wm = w >> 1, wn = w & 1;
    const int lhi = l >> 4, llo = l & 15;
    const int sw0 = ((lhi ^ (llo & 7)) << 3);
    const int sw1 = sw0 ^ 32;

    const int lin = blockIdx.x;
    const int xcd = lin & 7, j = lin >> 3;
    const int bm = xcd * 4 + (j & 3);
    const int bn = j >> 2;

    v4f acc[4][4];
    #pragma unroll
    for (int i = 0; i < 4; ++i)
        #pragma unroll
        for (int jj = 0; jj < 4; ++jj)
            #pragma unroll
            for (int r = 0; r < 4; ++r) acc[i][jj][r] = 0.f;

    const __bf16* Ab = A  + (size_t)bm * 128 * K;
    const __bf16* Bb = Bt + (size_t)bn * 128 * K;

    const int niter = K >> 6;
    for (int it = 0; it < niter; ++it) {
        if (it) __syncthreads();               // all waves done reading previous tile
        gemm_stage(Ab, Bb, As, Bs, K, it * 64, w, l);
        __syncthreads();                       // drain gl_lds for this tile
        #pragma unroll
        for (int kk = 0; kk < 64; kk += 32) {
            const int sw = kk ? sw1 : sw0;
            v8bf a[4], b[4];
            #pragma unroll
            for (int i = 0; i < 4; ++i)
                a[i] = *(const v8bf*)&As[(wm * 64 + i * 16 + llo) * 64 + sw];
            #pragma unroll
            for (int jj = 0; jj < 4; ++jj)
                b[jj] = *(const v8bf*)&Bs[(wn * 64 + jj * 16 + llo) * 64 + sw];
            #pragma unroll
            for (int i = 0; i < 4; ++i)
                #pragma unroll
                for (int jj = 0; jj < 4; ++jj)
                    acc[i][jj] = __builtin_amdgcn_mfma_f32_16x16x32_bf16(a[i], b[jj], acc[i][jj], 0, 0, 0);
        }
    }

    const int row0 = bm * 128 + wm * 64;
    const int col0 = bn * 128 + wn * 64;

    if (col0 < 2048) {   // Q / K region
        #pragma unroll
        for (int i = 0; i < 4; ++i) {
            int rbase = row0 + i * 16 + lhi * 4;
            #pragma unroll
            for (int jj = 0; jj < 4; ++jj) {
                int c = col0 + jj * 16 + llo;
                #pragma unroll
                for (int r = 0; r < 4; ++r)
                    qk_out[(size_t)(rbase + r) * 2048 + c] = (__bf16)acc[i][jj][r];
            }
        }
    } else {             // V region -> vt[(b*16+h)*64+s][t]
        #pragma unroll
        for (int i = 0; i < 4; ++i) {
            int rbase = row0 + i * 16 + lhi * 4;
            int bidx = rbase >> 10, t0 = rbase & 1023;
            #pragma unroll
            for (int jj = 0; jj < 4; ++jj) {
                int c = col0 + jj * 16 + llo - 2048;
                v4bf pk;
                #pragma unroll
                for (int r = 0; r < 4; ++r) pk[r] = (__bf16)acc[i][jj][r];
                *(v4bf*)&vt_out[((size_t)(bidx * NH + (c >> 6)) * HS + (c & 63)) * TT + t0] = pk;
            }
        }
    }
}

// -------- out-proj GEMM: 64x128 tiles, dbuf -> 512 blocks (r12-validated) --------
__global__ __launch_bounds__(256) void gemm_bt64_kernel(
    const __bf16* __restrict__ A, const __bf16* __restrict__ Bt, int K,
    float* __restrict__ f_out, const float* __restrict__ bias)
{
    __shared__ __align__(16) __bf16 As[2][64 * 64];
    __shared__ __align__(16) __bf16 Bs[2][128 * 64];
    const int tid = threadIdx.x;
    const int w = tid >> 6, l = tid & 63;
    const int wm = w & 1, wn = w >> 1;
    const int lhi = l >> 4, llo = l & 15;
    const int sw0 = ((lhi ^ (llo & 7)) << 3);
    const int sw1 = sw0 ^ 32;

    const int lin = blockIdx.x;
    const int xcd = lin & 7, j = lin >> 3;
    const int bm = xcd * 8 + (j & 7);
    const int bn = j >> 3;

    v4f acc[2][4];
    #pragma unroll
    for (int i = 0; i < 2; ++i)
        #pragma unroll
        for (int jj = 0; jj < 4; ++jj)
            #pragma unroll
            for (int r = 0; r < 4; ++r) acc[i][jj][r] = 0.f;

    const __bf16* Ab = A  + (size_t)bm * 64 * K;
    const __bf16* Bb = Bt + (size_t)bn * 128 * K;

    const int niter = K >> 6;
    {
        #pragma unroll
        for (int i = 0; i < 2; ++i) {
            int p = i * 256 + tid, row = p >> 3, lc = (p & 7) ^ (row & 7);
            gl_lds16(Ab + (size_t)row * K + lc * 8, As[0] + p * 8);
        }
        #pragma unroll
        for (int i = 0; i < 4; ++i) {
            int p = i * 256 + tid, row = p >> 3, lc = (p & 7) ^ (row & 7);
            gl_lds16(Bb + (size_t)row * K + lc * 8, Bs[0] + p * 8);
        }
    }

    for (int it = 0; it < niter; ++it) {
        const int buf = it & 1;
        __syncthreads();
        if (it + 1 < niter) {
            const int k0 = (it + 1) * 64;
            #pragma unroll
            for (int i = 0; i < 2; ++i) {
                int p = i * 256 + tid, row = p >> 3, lc = (p & 7) ^ (row & 7);
                gl_lds16(Ab + (size_t)row * K + k0 + lc * 8, As[buf ^ 1] + p * 8);
            }
            #pragma unroll
            for (int i = 0; i < 4; ++i) {
                int p = i * 256 + tid, row = p >> 3, lc = (p & 7) ^ (row & 7);
                gl_lds16(Bb + (size_t)row * K + k0 + lc * 8, Bs[buf ^ 1] + p * 8);
            }
        }
        #pragma unroll
        for (int kk = 0; kk < 64; kk += 32) {
            const int sw = kk ? sw1 : sw0;
            v8bf a[2], b[4];
            #pragma unroll
            for (int i = 0; i < 2; ++i)
                a[i] = *(const v8bf*)&As[buf][(wm * 32 + i * 16 + llo) * 64 + sw];
            #pragma unroll
            for (int jj = 0; jj < 4; ++jj)
                b[jj] = *(const v8bf*)&Bs[buf][(wn * 64 + jj * 16 + llo) * 64 + sw];
            #pragma unroll
            for (int i = 0; i < 2; ++i)
                #pragma unroll
                for (int jj = 0; jj < 4; ++jj)
                    acc[i][jj] = __builtin_amdgcn_mfma_f32_16x16x32_bf16(a[i], b[jj], acc[i][jj], 0, 0, 0);
        }
    }

    const int row0 = bm * 64 + wm * 32;
    const int col0 = bn * 128 + wn * 64;
    #pragma unroll
    for (int jj = 0; jj < 4; ++jj) {
        int c = col0 + jj * 16 + llo;
        float bv = bias[c];
        #pragma unroll
        for (int i = 0; i < 2; ++i) {
            int rbase = row0 + i * 16 + lhi * 4;
            #pragma unroll
            for (int r = 0; r < 4; ++r)
                f_out[(size_t)(rbase + r) * DE + c] = acc[i][jj][r] + bv;
        }
    }
}

// ---------------- flash attention v4 (r6/r10-validated best): dbuf staging + XOR swizzle ----------------
__device__ __forceinline__ v4f bf_mfma(v8bf a, v8bf b, v4f c) {
    return __builtin_amdgcn_mfma_f32_16x16x32_bf16(a, b, c, 0, 0, 0);
}

__device__ __forceinline__ void stage_kv(
    const __bf16* __restrict__ kb, const __bf16* __restrict__ vb,
    __bf16* Ksb, __bf16* Vsb, int k0, int tid)
{
    #pragma unroll
    for (int i = 0; i < 2; ++i) {
        int p   = i * 256 + tid;
        int row = p >> 3;
        int lc  = (p & 7) ^ (row & 7);
        gl_lds16(kb + (size_t)(k0 + row) * 2048 + lc * 8, Ksb + p * 8);
        gl_lds16(vb + (size_t)row * TT + k0 + lc * 8,     Vsb + p * 8);
    }
}

template<bool DIAG>
__device__ __forceinline__ void attn_compute(
    const __bf16* __restrict__ Ksb, const __bf16* __restrict__ Vsb,
    __bf16* __restrict__ PsW, int k0, int r0, int lhi, int llo, int sw0, int sw1,
    v8bf aq0, v8bf aq1, v4f (&o)[4], float (&l_part)[4])
{
    v4f sacc[4];
    #pragma unroll
    for (int n = 0; n < 4; ++n)
        #pragma unroll
        for (int r = 0; r < 4; ++r) sacc[n][r] = 0.f;
    #pragma unroll
    for (int n = 0; n < 4; ++n) {
        v8bf bk0 = *(const v8bf*)&Ksb[(n * 16 + llo) * 64 + sw0];
        v8bf bk1 = *(const v8bf*)&Ksb[(n * 16 + llo) * 64 + sw1];
        sacc[n] = bf_mfma(aq0, bk0, sacc[n]);
        sacc[n] = bf_mfma(aq1, bk1, sacc[n]);
    }

    float prob[4][4];
    #pragma unroll
    for (int n = 0; n < 4; ++n) {
        int colg = k0 + n * 16 + llo;
        #pragma unroll
        for (int r = 0; r < 4; ++r) {
            float s2 = sacc[n][r] * 0.18033688f;   // 0.125 * log2(e)
            if (DIAG) { int rowg = r0 + lhi * 4 + r; if (colg > rowg) s2 = -1e30f; }
            float p = exp2f(s2);
            prob[n][r] = p;
            l_part[r] += p;
        }
    }

    #pragma unroll
    for (int r = 0; r < 4; ++r)
        #pragma unroll
        for (int n = 0; n < 4; ++n)
            PsW[(lhi * 4 + r) * 72 + n * 16 + llo] = (__bf16)prob[n][r];

    #pragma unroll
    for (int kk = 0; kk < 64; kk += 32) {
        v8bf ap = *(const v8bf*)&PsW[llo * 72 + kk + lhi * 8];
        const int sw = kk ? sw1 : sw0;
        #pragma unroll
        for (int n = 0; n < 4; ++n) {
            v8bf bv = *(const v8bf*)&Vsb[(n * 16 + llo) * 64 + sw];
            o[n] = bf_mfma(ap, bv, o[n]);
        }
    }
}

__global__ __launch_bounds__(256) void attn_kernel(
    const __bf16* __restrict__ qk, const __bf16* __restrict__ vt,
    __bf16* __restrict__ att)
{
    __shared__ __align__(16) __bf16 Ks[2][64 * 64];
    __shared__ __align__(16) __bf16 Vs[2][64 * 64];
    __shared__ __align__(16) __bf16 Ps[4][16 * 72];

    const int tid = threadIdx.x;
    const int w = tid >> 6, l = tid & 63;
    const int lhi = l >> 4, llo = l & 15;
    const int sw0 = ((lhi ^ (llo & 7)) << 3);
    const int sw1 = sw0 ^ 32;
    const int bh = blockIdx.x & 63;          // same-bh blocks 64 apart -> same XCD
    const int qt = 15 - (blockIdx.x >> 6);   // longest blocks launch first
    const int b = bh >> 4, h = bh & 15;

    const __bf16* qbase = qk + (size_t)b * TT * 2048 + h * HS;
    const __bf16* kbase = qk + (size_t)b * TT * 2048 + 1024 + h * HS;
    const __bf16* vbase = vt + (size_t)bh * HS * TT;
    __bf16* PsW = &Ps[w][0];

    const int r0 = qt * 64 + w * 16;

    stage_kv(kbase, vbase, Ks[0], Vs[0], 0, tid);

    v8bf aq0 = *(const v8bf*)&qbase[(size_t)(r0 + llo) * 2048 + lhi * 8];
    v8bf aq1 = *(const v8bf*)&qbase[(size_t)(r0 + llo) * 2048 + 32 + lhi * 8];

    float l_part[4] = {0.f, 0.f, 0.f, 0.f};
    v4f o[4];
    #pragma unroll
    for (int n = 0; n < 4; ++n)
        #pragma unroll
        for (int r = 0; r < 4; ++r) o[n][r] = 0.f;

    for (int kt = 0; kt < qt; ++kt) {
        const int buf = kt & 1;
        __syncthreads();
        stage_kv(kbase, vbase, Ks[buf ^ 1], Vs[buf ^ 1], (kt + 1) * 64, tid);
        attn_compute<false>(Ks[buf], Vs[buf], PsW, kt * 64, r0, lhi, llo, sw0, sw1, aq0, aq1, o, l_part);
    }
    __syncthreads();
    attn_compute<true>(Ks[qt & 1], Vs[qt & 1], PsW, qt * 64, r0, lhi, llo, sw0, sw1, aq0, aq1, o, l_part);

    #pragma unroll
    for (int r = 0; r < 4; ++r) {
        float s = l_part[r];
        #pragma unroll
        for (int msk = 1; msk < 16; msk <<= 1) s += __shfl_xor(s, msk, 64);
        float inv = 1.f / s;
        int rowg = b * TT + r0 + lhi * 4 + r;
        #pragma unroll
        for (int n = 0; n < 4; ++n)
            att[(size_t)rowg * DE + h * HS + n * 16 + llo] = (__bf16)(o[n][r] * inv);
    }
}

extern "C" void kernel_launch(void* const* d_in, const int* in_sizes, int n_in,
                              void* d_out, int out_size, void* d_ws, size_t ws_size,
                              hipStream_t stream)
{
    const float* x  = (const float*)d_in[0];
    const float* Wq = (const float*)d_in[1];
    const float* Wk = (const float*)d_in[2];
    const float* Wv = (const float*)d_in[3];
    const float* Wo = (const float*)d_in[4];
    const float* bo = (const float*)d_in[5];
    float* out = (float*)d_out;

    char* ws = (char*)d_ws;
    __bf16* xb  = (__bf16*)(ws);                 // 8 MB   [4096][1024]
    __bf16* Wt  = (__bf16*)(ws + 8388608);       // 6 MB   [3072][1024]
    __bf16* Wob = (__bf16*)(ws + 14680064);      // 2 MB   [1024][1024]
    __bf16* qk  = (__bf16*)(ws + 16777216);      // 16 MB  [4096][2048]
    __bf16* vt  = (__bf16*)(ws + 33554432);      // 8 MB   [64][64][1024]
    __bf16* att = (__bf16*)(ws + 41943040);      // 8 MB   [4096][1024]

    // fused prep: casts (5120 blocks) + weight transpose (768 blocks)
    prep_all_kernel<<<5888, 256, 0, stream>>>(x, xb, Wo, Wob, Wq, Wk, Wv, Wt);
    // QKV: M=4096, N=3072, K=1024 -> 768 blocks, single-buffered, 3 blocks/CU co-resident
    gemm_bt_kernel<<<768, 256, 0, stream>>>(xb, Wt, 1024, qk, vt);
    // attention: 1024 blocks = 64 bh x 16 q-supertiles, longest first
    attn_kernel<<<1024, 256, 0, stream>>>(qk, vt, att);
    // out proj: M=4096, N=1024, K=1024 -> 512 blocks (8 xcd x 8 bm x 8 bn), 64x128 tiles
    gemm_bt64_kernel<<<512, 256, 0, stream>>>(att, Wob, 1024, out, bo);
}